// Round 9
// baseline (20.624 us; speedup 1.0000x reference)
//
#include <hip/hip_runtime.h>

constexpr int N    = 8192;
constexpr int BLK  = 256;
constexpr int BX   = 128;      // x-points per block
constexpr int BY   = 2048;     // y-points per block (one y-range)
constexpr int NYR  = N / BY;   // 4 y-ranges
constexpr int P    = 8;        // x-points per thread
constexpr int NSL  = 16;       // y-slices per block
constexpr int SY   = BY / NSL; // 128 y per slice
constexpr int SPAD = SY + 1;   // 129 float4s: +4 banks per slice
constexpr int RPAD = BX + 4;   // 132: +4 banks per slice row

// grid 512: dir = b>>8, xbk = (b>>2)&63, yr = b&3.
// Inner loop software-pipelined 2-deep; block 0 zeroes stage2's counter.
__global__ __launch_bounds__(BLK) void chamfer_stage1(
    const float* __restrict__ pred, const float* __restrict__ label,
    float* __restrict__ minbuf, unsigned int* __restrict__ counter)
{
    if (blockIdx.x == 0 && threadIdx.x == 0)
        __hip_atomic_store(counter, 0u, __ATOMIC_RELAXED, __HIP_MEMORY_SCOPE_AGENT);

    int b   = blockIdx.x;
    int dir = b >> 8;
    int xbk = (b >> 2) & 63;
    int yr  = b & 3;

    const float* A = dir ? label : pred;   // query set
    const float* B = dir ? pred  : label;  // target set

    __shared__ float4 sy[NSL * SPAD];      // 33 KB
    __shared__ float  red[NSL * RPAD];     // 8.4 KB

    int u  = threadIdx.x & 15;
    int ys = threadIdx.x >> 4;

    float cxa[P], cxb[P], cxc[P], xn[P], m[P];
    #pragma unroll
    for (int k = 0; k < P; ++k) {
        int idx = xbk * BX + k * 16 + u;
        float a = A[3*idx], c = A[3*idx+1], d = A[3*idx+2];
        cxa[k] = -2.f * a;  cxb[k] = -2.f * c;  cxc[k] = -2.f * d;
        xn[k] = a*a + c*c + d*d;
        m[k]  = 3.4e38f;
    }

    for (int i = threadIdx.x; i < BY; i += BLK) {
        int g = yr * BY + i;
        float a = B[3*g], c = B[3*g+1], d = B[3*g+2];
        sy[(i >> 7) * SPAD + (i & (SY-1))] = make_float4(a, c, d, a*a + c*c + d*d);
    }
    __syncthreads();

    const float4* s = &sy[ys * SPAD];
    float4 y0 = s[0], y1 = s[1];
    #pragma unroll 8
    for (int j = 0; j < SY - 2; j += 2) {
        float4 t0 = s[j + 2], t1 = s[j + 3];   // prefetch next pair
        #pragma unroll
        for (int k = 0; k < P; ++k) {
            float sa = fmaf(cxa[k], y0.x, fmaf(cxb[k], y0.y, fmaf(cxc[k], y0.z, y0.w)));
            float sb = fmaf(cxa[k], y1.x, fmaf(cxb[k], y1.y, fmaf(cxc[k], y1.z, y1.w)));
            m[k] = fminf(fminf(sa, sb), m[k]);   // v_min3_f32
        }
        y0 = t0; y1 = t1;
    }
    #pragma unroll
    for (int k = 0; k < P; ++k) {              // epilogue pair
        float sa = fmaf(cxa[k], y0.x, fmaf(cxb[k], y0.y, fmaf(cxc[k], y0.z, y0.w)));
        float sb = fmaf(cxa[k], y1.x, fmaf(cxb[k], y1.y, fmaf(cxc[k], y1.z, y1.w)));
        m[k] = fminf(fminf(sa, sb), m[k]);
    }

    #pragma unroll
    for (int k = 0; k < P; ++k)
        red[ys * RPAD + k * 16 + u] = fmaxf(m[k] + xn[k], 0.f);
    __syncthreads();

    if (threadIdx.x < BX) {
        float v = red[threadIdx.x];
        #pragma unroll
        for (int q = 1; q < NSL; ++q)
            v = fminf(v, red[q * RPAD + threadIdx.x]);
        minbuf[yr * (2 * N) + dir * N + xbk * BX + threadIdx.x] = v;
    }
}

// 16 blocks x 256: column mins over 4 ranges, sqrt, block sum -> bsum;
// threadfence-counter last block sums the 16 partials -> out[0].
__global__ __launch_bounds__(256) void chamfer_stage2(
    const float4* __restrict__ minbuf4, float* __restrict__ bsum,
    unsigned int* __restrict__ counter, float* __restrict__ out)
{
    int g = blockIdx.x * 256 + threadIdx.x;   // float4 index in [0, 4096)
    float4 v = minbuf4[g];
    #pragma unroll
    for (int r = 1; r < NYR; ++r) {
        float4 w = minbuf4[r * 4096 + g];
        v.x = fminf(v.x, w.x); v.y = fminf(v.y, w.y);
        v.z = fminf(v.z, w.z); v.w = fminf(v.w, w.w);
    }
    float s = sqrtf(v.x) + sqrtf(v.y) + sqrtf(v.z) + sqrtf(v.w);
    for (int off = 32; off; off >>= 1) s += __shfl_down(s, off);
    __shared__ float r2[4];
    __shared__ unsigned int isLast;
    if ((threadIdx.x & 63) == 0) r2[threadIdx.x >> 6] = s;
    __syncthreads();
    if (threadIdx.x == 0) {
        bsum[blockIdx.x] = r2[0] + r2[1] + r2[2] + r2[3];
        __threadfence();                       // bsum visible before counter bump
        unsigned int old = atomicAdd(counter, 1u);
        isLast = (old == 15u) ? 1u : 0u;       // counter zeroed by stage1
    }
    __syncthreads();
    if (!isLast) return;

    __threadfence();
    if (threadIdx.x < 64) {
        float t = (threadIdx.x < 16)
            ? __hip_atomic_load(&bsum[threadIdx.x], __ATOMIC_RELAXED,
                                __HIP_MEMORY_SCOPE_AGENT)
            : 0.f;
        for (int off = 8; off; off >>= 1) t += __shfl_down(t, off, 64);
        if (threadIdx.x == 0) out[0] = t * (1.0f / N);  // mean_x + mean_y
    }
}

extern "C" void kernel_launch(void* const* d_in, const int* in_sizes, int n_in,
                              void* d_out, int out_size, void* d_ws, size_t ws_size,
                              hipStream_t stream) {
    const float* pred  = (const float*)d_in[0];
    const float* label = (const float*)d_in[1];
    float* out    = (float*)d_out;
    float* minbuf = (float*)d_ws;                 // NYR*2N floats = 256 KB
    float* bsum   = minbuf + NYR * 2 * N;         // 16 floats
    unsigned int* counter = (unsigned int*)(bsum + 16);

    chamfer_stage1<<<dim3(2 * (N / BX) * NYR), dim3(BLK), 0, stream>>>(pred, label, minbuf, counter);
    chamfer_stage2<<<dim3(16), dim3(256), 0, stream>>>((const float4*)minbuf, bsum, counter, out);
}